// Round 3
// baseline (788.322 us; speedup 1.0000x reference)
//
#include <hip/hip_runtime.h>

typedef unsigned int u32;
typedef unsigned short u16;
typedef __attribute__((ext_vector_type(8))) short short8;
typedef __attribute__((ext_vector_type(16))) float f32x16;

// Problem constants
#define NA   50000      // atoms
#define MN   12         // neighbors
#define FD   128        // atom feature len
#define KD   64         // nbr feature len
#define NMR  600000     // NA*MN edge rows
#define KIN  320        // 2F+K
#define NT2  9375       // NMR/64 tiles (pass A)
#define NBLK2 512       // pass-A persistent blocks
#define NBLKB 6250      // pass-B blocks: 8 atoms = 96 edge rows each
#define BN_EPS 1e-5f
#define LOG2E 1.4426950408889634f
#define LN2   0.6931471805599453f

// ---- fast transcendentals: raw v_exp_f32 / v_log_f32 / v_rcp_f32 ----
#if __has_builtin(__builtin_amdgcn_exp2f)
#define EXP2F(x) __builtin_amdgcn_exp2f(x)
#else
#define EXP2F(x) exp2f(x)
#endif
#if __has_builtin(__builtin_amdgcn_logf)
#define LOG2F(x) __builtin_amdgcn_logf(x)
#else
#define LOG2F(x) log2f(x)
#endif
#if __has_builtin(__builtin_amdgcn_rcpf)
#define RCPF(x) __builtin_amdgcn_rcpf(x)
#else
#define RCPF(x) (1.f / (x))
#endif

__device__ __forceinline__ float fast_sigmoid(float x) {
    return RCPF(1.f + EXP2F(-x * LOG2E));    // 1/(1+e^-x)
}
__device__ __forceinline__ float fast_softplus(float x) {
    float e = EXP2F(-fabsf(x) * LOG2E);      // e^{-|x|}
    return fmaxf(x, 0.f) + LN2 * LOG2F(1.f + e);
}

// ---- manual bf16 (RNE) helpers ----
__device__ __forceinline__ u32 f2bf_bits(float f) {
    u32 u = __float_as_uint(f);
    return u + 0x7fffu + ((u >> 16) & 1u);
}
__device__ __forceinline__ u32 pack2(float lo, float hi) {
    return (f2bf_bits(lo) >> 16) | (f2bf_bits(hi) & 0xffff0000u);
}
__device__ __forceinline__ float bflo(u32 u) { return __uint_as_float(u << 16); }
__device__ __forceinline__ float bfhi(u32 u) { return __uint_as_float(u & 0xffff0000u); }
__device__ __forceinline__ short8 pack8(float4 x, float4 y) {
    union { short8 s; uint4 u; } cv;
    cv.u = make_uint4(pack2(x.x, x.y), pack2(x.z, x.w),
                      pack2(y.x, y.y), pack2(y.z, y.w));
    return cv.s;
}

// ---------------------------------------------------------------------------
// K1 (MFMA, persistent): P12[n][0:256] = atom@W1^T, [256:512] = atom@W2^T.
// REWRITTEN: 1024 persistent blocks (4/CU). Block owns a 128-col group
// (cgrp = blockIdx&3), wave owns 64 cols -> bfrag[2][8] = 64 VGPR stationary,
// loaded ONCE; grid-stride over ~3 row-chunks of 64. VGPR ~150 -> 12 waves/CU
// (vs old ~230 VGPR, 8 waves/CU, 1564 one-shot blocks reloading W each).
// ---------------------------------------------------------------------------
__global__ __launch_bounds__(256, 3) void k1_p12(const float* __restrict__ atom,
                                                 const float* __restrict__ W,
                                                 u16* __restrict__ P12) {
    const int t  = threadIdx.x;
    const int w  = t >> 6;
    const int L  = t & 63;
    const int rg = w & 1, cw = w >> 1;
    const int lr = L & 31, lk = L >> 5;

    const int cgrp    = blockIdx.x & 3;          // which 128-col group of 512
    const int yb      = cgrp >> 1;               // 0: P1 (k 0..127), 1: P2
    const int kw      = yb * 128;
    const int colbase = (cgrp & 1) * 128 + cw * 64;   // W-row base in [0,256)

    // stationary B frags: wave covers cols colbase + ct*32 + lr, ct<2
    short8 bfrag[2][8];
#pragma unroll
    for (int ct = 0; ct < 2; ct++) {
        const float* wr = &W[(size_t)(colbase + ct * 32 + lr) * KIN + kw];
#pragma unroll
        for (int s = 0; s < 8; s++) {
            float4 x = *(const float4*)&wr[s * 16 + lk * 8];
            float4 y = *(const float4*)&wr[s * 16 + lk * 8 + 4];
            bfrag[ct][s] = pack8(x, y);
        }
    }

    // grid-stride over 782 row-chunks of 64 (256 blocks share each cgrp)
    for (int ci = (blockIdx.x >> 2); ci < 782; ci += 256) {
        const int r0 = ci * 64 + rg * 32;
        int row = r0 + lr; if (row > NA - 1) row = NA - 1;
        const float* ar = &atom[(size_t)row * FD];
        short8 afrag[8];
#pragma unroll
        for (int s = 0; s < 8; s++) {
            float4 x = *(const float4*)&ar[s * 16 + lk * 8];
            float4 y = *(const float4*)&ar[s * 16 + lk * 8 + 4];
            afrag[s] = pack8(x, y);
        }
        f32x16 acc[2];
#pragma unroll
        for (int ct = 0; ct < 2; ct++)
#pragma unroll
            for (int p = 0; p < 16; p++) acc[ct][p] = 0.f;
#pragma unroll
        for (int s = 0; s < 8; s++)
#pragma unroll
            for (int ct = 0; ct < 2; ct++)
                acc[ct] = __builtin_amdgcn_mfma_f32_32x32x16_bf16(
                              afrag[s], bfrag[ct][s], acc[ct], 0, 0, 0);
#pragma unroll
        for (int ct = 0; ct < 2; ct++) {
            const int c = colbase + ct * 32 + lr;
#pragma unroll
            for (int p = 0; p < 16; p++) {
                int r = r0 + (p & 3) + 8 * (p >> 2) + 4 * lk;
                if (r < NA)
                    P12[(size_t)r * 512 + yb * 256 + c] =
                        (u16)(f2bf_bits(acc[ct][p]) >> 16);
            }
        }
    }
}

// ---------------------------------------------------------------------------
// K2 (pass A, BN1 stats): round-2 structure, but C staged as bf16 -> LDS
// 64 KB -> 32 KB, occupancy cap 2 -> 4 blocks/CU (VGPR <= 128 via
// launch_bounds(256,4)). bf16 staging of Q already proven accuracy-safe (k3).
// ---------------------------------------------------------------------------
__global__ __launch_bounds__(256, 4) void k2_stats(const float* __restrict__ nbr,
                                                   const int* __restrict__ nidx,
                                                   const float* __restrict__ W,
                                                   const u16* __restrict__ P12,
                                                   float* __restrict__ partial1) {
    __shared__ u16 C16[64 * 256];     // 32 KB bf16 staging
    const int t  = threadIdx.x;
    const int w  = t >> 6;
    const int L  = t & 63;
    const int rg = w & 1;
    const int cg = w >> 1;
    const int lr = L & 31;
    const int lk = L >> 5;

    // stationary B frags: B[k][n] = W[n][256+k]
    short8 bfrag[4][4];
#pragma unroll
    for (int ct = 0; ct < 4; ct++) {
        const float* wr = &W[(size_t)(cg * 128 + ct * 32 + lr) * KIN + 256];
#pragma unroll
        for (int s = 0; s < 4; s++) {
            float4 x = *(const float4*)&wr[s * 16 + lk * 8];
            float4 y = *(const float4*)&wr[s * 16 + lk * 8 + 4];
            bfrag[ct][s] = pack8(x, y);
        }
    }

    const int c0 = (t & 63) * 4;
    float ssum[4] = {0.f, 0.f, 0.f, 0.f};
    float ssq[4]  = {0.f, 0.f, 0.f, 0.f};

    int tile = blockIdx.x;
    float4 a0[4], a1[4];
    {
        const float* ar = &nbr[(size_t)(tile * 64 + rg * 32 + lr) * KD];
#pragma unroll
        for (int s = 0; s < 4; s++) {
            a0[s] = *(const float4*)&ar[s * 16 + lk * 8];
            a1[s] = *(const float4*)&ar[s * 16 + lk * 8 + 4];
        }
    }

    for (; tile < NT2; tile += NBLK2) {
        short8 af[4];
#pragma unroll
        for (int s = 0; s < 4; s++) af[s] = pack8(a0[s], a1[s]);

        // prefetch next tile's A rows (flies over C-stage + epilogue)
        const int next = tile + NBLK2;
        if (next < NT2) {
            const float* ar = &nbr[(size_t)(next * 64 + rg * 32 + lr) * KD];
#pragma unroll
            for (int s = 0; s < 4; s++) {
                a0[s] = *(const float4*)&ar[s * 16 + lk * 8];
                a1[s] = *(const float4*)&ar[s * 16 + lk * 8 + 4];
            }
        }

        f32x16 acc[4];
#pragma unroll
        for (int ct = 0; ct < 4; ct++)
#pragma unroll
            for (int p = 0; p < 16; p++) acc[ct][p] = 0.f;
#pragma unroll
        for (int s = 0; s < 4; s++)
#pragma unroll
            for (int ct = 0; ct < 4; ct++)
                acc[ct] = __builtin_amdgcn_mfma_f32_32x32x16_bf16(
                              af[s], bfrag[ct][s], acc[ct], 0, 0, 0);

        __syncthreads();   // previous tile's epilogue reads complete
#pragma unroll
        for (int ct = 0; ct < 4; ct++) {
            const int col = cg * 128 + ct * 32 + lr;
#pragma unroll
            for (int p = 0; p < 16; p++) {
                int r = rg * 32 + (p & 3) + 8 * (p >> 2) + 4 * lk;
                C16[r * 256 + col] = (u16)(f2bf_bits(acc[ct][p]) >> 16);
            }
        }
        __syncthreads();

        // linear epilogue: wave w -> rows w, w+4, ..., w+60
#pragma unroll 8
        for (int rr = 0; rr < 16; rr++) {
            const int lrow = rr * 4 + w;
            const int g    = tile * 64 + lrow;
            const u32 n    = (u32)g / 12u;
            const int iv   = nidx[g];
            const float mk = (iv != 0) ? 1.f : 0.f;
            uint2 qv = *(const uint2*)&C16[lrow * 256 + c0];
            uint2 u1 = *(const uint2*)&P12[(size_t)n * 512 + c0];
            uint2 u2 = *(const uint2*)&P12[(size_t)iv * 512 + 256 + c0];
            float v0 = bflo(u1.x) + mk * (bflo(u2.x) + bflo(qv.x));
            float v1 = bfhi(u1.x) + mk * (bfhi(u2.x) + bfhi(qv.x));
            float v2 = bflo(u1.y) + mk * (bflo(u2.y) + bflo(qv.y));
            float v3 = bfhi(u1.y) + mk * (bfhi(u2.y) + bfhi(qv.y));
            ssum[0] += v0; ssq[0] = fmaf(v0, v0, ssq[0]);
            ssum[1] += v1; ssq[1] = fmaf(v1, v1, ssq[1]);
            ssum[2] += v2; ssq[2] = fmaf(v2, v2, ssq[2]);
            ssum[3] += v3; ssq[3] = fmaf(v3, v3, ssq[3]);
        }
    }

    // block-level column reduction -> partial1[block][512]
    __syncthreads();
    float* red = (float*)C16;
#pragma unroll
    for (int qq = 0; qq < 4; qq++) red[w * 256 + c0 + qq] = ssum[qq];
    __syncthreads();
    {
        float s = red[t] + red[256 + t] + red[512 + t] + red[768 + t];
        partial1[(size_t)blockIdx.x * 512 + t] = s;
    }
    __syncthreads();
#pragma unroll
    for (int qq = 0; qq < 4; qq++) red[w * 256 + c0 + qq] = ssq[qq];
    __syncthreads();
    {
        float s = red[t] + red[256 + t] + red[512 + t] + red[768 + t];
        partial1[(size_t)blockIdx.x * 512 + 256 + t] = s;
    }
}

// ---------------------------------------------------------------------------
// K2b: finalize BN1 -> bn1[c]=scale, bn1[256+c]=shift
// ---------------------------------------------------------------------------
__global__ __launch_bounds__(64) void k2b_bn1(const float* __restrict__ partial1,
                                              const float* __restrict__ gamma1,
                                              const float* __restrict__ beta1,
                                              float* __restrict__ bn1) {
    const int c = blockIdx.x;
    const int t = threadIdx.x;
    double s = 0.0, q = 0.0;
    for (int b = t; b < NBLK2; b += 64) {
        s += (double)partial1[(size_t)b * 512 + c];
        q += (double)partial1[(size_t)b * 512 + 256 + c];
    }
#pragma unroll
    for (int off = 32; off > 0; off >>= 1) {
        s += __shfl_down(s, off);
        q += __shfl_down(q, off);
    }
    if (t == 0) {
        double mean = s / (double)NMR;
        double var  = q / (double)NMR - mean * mean;
        float scale = gamma1[c] * rsqrtf((float)var + BN_EPS);
        bn1[c]       = scale;
        bn1[256 + c] = fmaf(-(float)mean, scale, beta1[c]);
    }
}

// ---------------------------------------------------------------------------
// K3 (pass B): UNCHANGED from round 2 (172 us, control for this round).
// Block = 96 edge rows = 8 atoms; MFMA Q -> bf16 LDS; column-parallel
// epilogue with coalesced 256B P12 bursts; register accumulation.
// ---------------------------------------------------------------------------
__global__ __launch_bounds__(256, 3) void k3_fused(const float* __restrict__ nbr,
                                                   const int* __restrict__ nidx,
                                                   const float* __restrict__ W,
                                                   const u16* __restrict__ P12,
                                                   const float* __restrict__ bn1,
                                                   float* __restrict__ nsum,
                                                   float* __restrict__ partial2) {
    __shared__ u16 Q[96 * 256];   // 48 KB bf16 Q-tile
    const int t  = threadIdx.x;
    const int w  = t >> 6;
    const int L  = t & 63;
    const int lr = L & 31, lk = L >> 5;

    // stationary B frags: cols w*64 + ct*32 + lr, k in [256,320)
    short8 bfrag[2][4];
#pragma unroll
    for (int ct = 0; ct < 2; ct++) {
        const float* wr = &W[(size_t)(w * 64 + ct * 32 + lr) * KIN + 256];
#pragma unroll
        for (int s = 0; s < 4; s++) {
            float4 x = *(const float4*)&wr[s * 16 + lk * 8];
            float4 y = *(const float4*)&wr[s * 16 + lk * 8 + 4];
            bfrag[ct][s] = pack8(x, y);
        }
    }

    const int rbase = blockIdx.x * 96;
#pragma unroll 1
    for (int st = 0; st < 3; st++) {
        const float* ar = &nbr[(size_t)(rbase + st * 32 + lr) * KD + lk * 8];
        f32x16 acc[2];
#pragma unroll
        for (int p = 0; p < 16; p++) { acc[0][p] = 0.f; acc[1][p] = 0.f; }
#pragma unroll
        for (int s = 0; s < 4; s++) {
            float4 x = *(const float4*)&ar[s * 16];
            float4 y = *(const float4*)&ar[s * 16 + 4];
            short8 af = pack8(x, y);
            acc[0] = __builtin_amdgcn_mfma_f32_32x32x16_bf16(af, bfrag[0][s], acc[0], 0, 0, 0);
            acc[1] = __builtin_amdgcn_mfma_f32_32x32x16_bf16(af, bfrag[1][s], acc[1], 0, 0, 0);
        }
#pragma unroll
        for (int ct = 0; ct < 2; ct++) {
            const int col = w * 64 + ct * 32 + lr;
#pragma unroll
            for (int p = 0; p < 16; p++) {
                const int row = st * 32 + (p & 3) + 8 * (p >> 2) + 4 * lk;
                Q[row * 256 + col] = (u16)(f2bf_bits(acc[ct][p]) >> 16);
            }
        }
    }
    __syncthreads();

    // epilogue: thread -> (atom a, filter cols c0..c0+3; core cols +128)
    const int a  = t >> 5;            // 0..7
    const int c0 = (t & 31) * 4;      // filter col base
    const int n  = blockIdx.x * 8 + a;

    float4 scf = *(const float4*)&bn1[c0];
    float4 shf = *(const float4*)&bn1[256 + c0];
    float4 scc = *(const float4*)&bn1[128 + c0];
    float4 shc = *(const float4*)&bn1[384 + c0];

    uint2 u1f = *(const uint2*)&P12[(size_t)n * 512 + c0];
    uint2 u1c = *(const uint2*)&P12[(size_t)n * 512 + 128 + c0];
    const float p1f0 = bflo(u1f.x), p1f1 = bfhi(u1f.x), p1f2 = bflo(u1f.y), p1f3 = bfhi(u1f.y);
    const float p1c0 = bflo(u1c.x), p1c1 = bfhi(u1c.x), p1c2 = bflo(u1c.y), p1c3 = bfhi(u1c.y);

    float s4[4] = {0.f, 0.f, 0.f, 0.f};
#pragma unroll
    for (int m = 0; m < 12; m++) {
        const int g  = n * 12 + m;
        const int iv = nidx[g];
        const float mk = (iv != 0) ? 1.f : 0.f;
        const int row = a * 12 + m;
        uint2 qf  = *(const uint2*)&Q[row * 256 + c0];
        uint2 qc  = *(const uint2*)&Q[row * 256 + 128 + c0];
        uint2 u2f = *(const uint2*)&P12[(size_t)iv * 512 + 256 + c0];
        uint2 u2c = *(const uint2*)&P12[(size_t)iv * 512 + 384 + c0];

        float vf0 = p1f0 + mk * (bflo(u2f.x) + bflo(qf.x));
        float vf1 = p1f1 + mk * (bfhi(u2f.x) + bfhi(qf.x));
        float vf2 = p1f2 + mk * (bflo(u2f.y) + bflo(qf.y));
        float vf3 = p1f3 + mk * (bfhi(u2f.y) + bfhi(qf.y));
        float vc0 = p1c0 + mk * (bflo(u2c.x) + bflo(qc.x));
        float vc1 = p1c1 + mk * (bfhi(u2c.x) + bfhi(qc.x));
        float vc2 = p1c2 + mk * (bflo(u2c.y) + bflo(qc.y));
        float vc3 = p1c3 + mk * (bfhi(u2c.y) + bfhi(qc.y));

        float xf0 = fmaf(vf0, scf.x, shf.x), xc0 = fmaf(vc0, scc.x, shc.x);
        float xf1 = fmaf(vf1, scf.y, shf.y), xc1 = fmaf(vc1, scc.y, shc.y);
        float xf2 = fmaf(vf2, scf.z, shf.z), xc2 = fmaf(vc2, scc.z, shc.z);
        float xf3 = fmaf(vf3, scf.w, shf.w), xc3 = fmaf(vc3, scc.w, shc.w);

        s4[0] += fast_sigmoid(xf0) * fast_softplus(xc0) * mk;
        s4[1] += fast_sigmoid(xf1) * fast_softplus(xc1) * mk;
        s4[2] += fast_sigmoid(xf2) * fast_softplus(xc2) * mk;
        s4[3] += fast_sigmoid(xf3) * fast_softplus(xc3) * mk;
    }

    *(float4*)&nsum[(size_t)n * 128 + c0] = make_float4(s4[0], s4[1], s4[2], s4[3]);

    // BN2 partials: reuse Q LDS as float scratch (8 KB needed)
    __syncthreads();
    float* red = (float*)Q;
#pragma unroll
    for (int j = 0; j < 4; j++) {
        red[a * 128 + c0 + j]        = s4[j];
        red[1024 + a * 128 + c0 + j] = s4[j] * s4[j];
    }
    __syncthreads();
    if (t < 128) {
        float s = 0.f, q = 0.f;
#pragma unroll
        for (int a2 = 0; a2 < 8; a2++) {
            s += red[a2 * 128 + t];
            q += red[1024 + a2 * 128 + t];
        }
        partial2[(size_t)blockIdx.x * 256 + t]       = s;
        partial2[(size_t)blockIdx.x * 256 + 128 + t] = q;
    }
}

// ---------------------------------------------------------------------------
// K3b: finalize BN2 -> bn2[c]=scale, bn2[128+c]=shift
// ---------------------------------------------------------------------------
__global__ __launch_bounds__(64) void k3b_bn2(const float* __restrict__ partial2,
                                              const float* __restrict__ gamma2,
                                              const float* __restrict__ beta2,
                                              float* __restrict__ bn2) {
    const int c = blockIdx.x;
    const int t = threadIdx.x;
    double s = 0.0, q = 0.0;
    for (int b = t; b < NBLKB; b += 64) {
        s += (double)partial2[(size_t)b * 256 + c];
        q += (double)partial2[(size_t)b * 256 + 128 + c];
    }
#pragma unroll
    for (int off = 32; off > 0; off >>= 1) {
        s += __shfl_down(s, off);
        q += __shfl_down(q, off);
    }
    if (t == 0) {
        double mean = s / (double)NA;
        double var  = q / (double)NA - mean * mean;
        float scale = gamma2[c] * rsqrtf((float)var + BN_EPS);
        bn2[c]       = scale;
        bn2[128 + c] = fmaf(-(float)mean, scale, beta2[c]);
    }
}

// ---------------------------------------------------------------------------
// K4: out = softplus(atom_in + nbr_sumed*scale2 + shift2)
// ---------------------------------------------------------------------------
__global__ __launch_bounds__(256) void k4_out(const float* __restrict__ atom,
                                              const float* __restrict__ nsum,
                                              const float* __restrict__ bn2,
                                              float* __restrict__ out) {
    const int i  = blockIdx.x * 256 + threadIdx.x;   // float4 index, 1.6M exact
    const int c0 = (i & 31) * 4;
    float4 a = ((const float4*)atom)[i];
    float4 s = ((const float4*)nsum)[i];
    float4 r;
    r.x = fast_softplus(a.x + fmaf(s.x, bn2[c0 + 0], bn2[128 + c0 + 0]));
    r.y = fast_softplus(a.y + fmaf(s.y, bn2[c0 + 1], bn2[128 + c0 + 1]));
    r.z = fast_softplus(a.z + fmaf(s.z, bn2[c0 + 2], bn2[128 + c0 + 2]));
    r.w = fast_softplus(a.w + fmaf(s.w, bn2[c0 + 3], bn2[128 + c0 + 3]));
    ((float4*)out)[i] = r;
}

// ---------------------------------------------------------------------------
extern "C" void kernel_launch(void* const* d_in, const int* in_sizes, int n_in,
                              void* d_out, int out_size, void* d_ws, size_t ws_size,
                              hipStream_t stream) {
    const float* atom   = (const float*)d_in[0];
    const float* nbr    = (const float*)d_in[1];
    const int*   nidx   = (const int*)d_in[2];
    const float* W      = (const float*)d_in[3];
    // d_in[4] = b : unused — cancels exactly through BN1 mean subtraction
    const float* gamma1 = (const float*)d_in[5];
    const float* beta1  = (const float*)d_in[6];
    const float* gamma2 = (const float*)d_in[7];
    const float* beta2  = (const float*)d_in[8];
    float* out = (float*)d_out;

    // ws layout: P12 bf16 (51.2MB) | nsum (25.6MB) | partial1 | partial2 | bn
    u16* P12        = (u16*)d_ws;
    float* nsum     = (float*)(P12 + (size_t)NA * 512);
    float* partial1 = nsum + (size_t)NA * 128;
    float* partial2 = partial1 + (size_t)NBLK2 * 512;
    float* bn1      = partial2 + (size_t)NBLKB * 256;
    float* bn2      = bn1 + 512;

    k1_p12  <<<1024,  256, 0, stream>>>(atom, W, P12);
    k2_stats<<<NBLK2, 256, 0, stream>>>(nbr, nidx, W, P12, partial1);
    k2b_bn1 <<<256,    64, 0, stream>>>(partial1, gamma1, beta1, bn1);
    k3_fused<<<NBLKB, 256, 0, stream>>>(nbr, nidx, W, P12, bn1, nsum, partial2);
    k3b_bn2 <<<128,    64, 0, stream>>>(partial2, gamma2, beta2, bn2);
    k4_out  <<<6250,  256, 0, stream>>>(atom, nsum, bn2, out);
}

// Round 4
// 522.483 us; speedup vs baseline: 1.5088x; 1.5088x over previous
//
#include <hip/hip_runtime.h>

typedef unsigned int u32;
typedef unsigned short u16;
typedef __attribute__((ext_vector_type(8))) short short8;
typedef __attribute__((ext_vector_type(16))) float f32x16;

// Problem constants
#define NA   50000      // atoms
#define MN   12         // neighbors
#define FD   128        // atom feature len
#define KD   64         // nbr feature len
#define NMR  600000     // NA*MN edge rows
#define KIN  320        // 2F+K
#define NT2  9375       // NMR/64 tiles (pass A)
#define NBLK2 512       // pass-A persistent blocks
#define NBLKB 6250      // pass-B blocks: 8 atoms = 96 edge rows each
#define BN_EPS 1e-5f
#define LOG2E 1.4426950408889634f
#define LN2   0.6931471805599453f

// ---- fast transcendentals: raw v_exp_f32 / v_log_f32 / v_rcp_f32 ----
#if __has_builtin(__builtin_amdgcn_exp2f)
#define EXP2F(x) __builtin_amdgcn_exp2f(x)
#else
#define EXP2F(x) exp2f(x)
#endif
#if __has_builtin(__builtin_amdgcn_logf)
#define LOG2F(x) __builtin_amdgcn_logf(x)
#else
#define LOG2F(x) log2f(x)
#endif
#if __has_builtin(__builtin_amdgcn_rcpf)
#define RCPF(x) __builtin_amdgcn_rcpf(x)
#else
#define RCPF(x) (1.f / (x))
#endif

__device__ __forceinline__ float fast_sigmoid(float x) {
    return RCPF(1.f + EXP2F(-x * LOG2E));    // 1/(1+e^-x)
}
__device__ __forceinline__ float fast_softplus(float x) {
    float e = EXP2F(-fabsf(x) * LOG2E);      // e^{-|x|}
    return fmaxf(x, 0.f) + LN2 * LOG2F(1.f + e);
}

// ---- manual bf16 (RNE) helpers ----
__device__ __forceinline__ u32 f2bf_bits(float f) {
    u32 u = __float_as_uint(f);
    return u + 0x7fffu + ((u >> 16) & 1u);
}
__device__ __forceinline__ u32 pack2(float lo, float hi) {
    return (f2bf_bits(lo) >> 16) | (f2bf_bits(hi) & 0xffff0000u);
}
__device__ __forceinline__ float bflo(u32 u) { return __uint_as_float(u << 16); }
__device__ __forceinline__ float bfhi(u32 u) { return __uint_as_float(u & 0xffff0000u); }
__device__ __forceinline__ short8 pack8(float4 x, float4 y) {
    union { short8 s; uint4 u; } cv;
    cv.u = make_uint4(pack2(x.x, x.y), pack2(x.z, x.w),
                      pack2(y.x, y.y), pack2(y.z, y.w));
    return cv.s;
}

// ---------------------------------------------------------------------------
// K1 (MFMA, persistent, NO col-split): P12[n][0:256]=atom@W1^T,
// [256:512]=atom@W2^T. Grid (256,2): block keeps round-0's exact inner
// structure (wave w: rows 32*(w&1), cols 128*(w>>1) of yb-half; bfrag[4][8]
// stationary = W loaded+packed ONCE per block) and grid-strides over ~3
// row-chunks of 64. Atom traffic & store pattern identical to round 0.
// NO min-wave forcing (round-3 lesson: forcing past VGPR budget => spills).
// ---------------------------------------------------------------------------
__global__ __launch_bounds__(256) void k1_p12(const float* __restrict__ atom,
                                              const float* __restrict__ W,
                                              u16* __restrict__ P12) {
    const int t  = threadIdx.x;
    const int w  = t >> 6;
    const int L  = t & 63;
    const int rg = w & 1, cg = w >> 1;
    const int lr = L & 31, lk = L >> 5;
    const int yb = blockIdx.y;
    const int kw = yb * 128;

    // stationary B frags: lane holds B[k = s*16 + 8*lk + j][n = cg*128 + ct*32 + lr]
    short8 bfrag[4][8];
#pragma unroll
    for (int ct = 0; ct < 4; ct++) {
        const float* wr = &W[(size_t)(cg * 128 + ct * 32 + lr) * KIN + kw];
#pragma unroll
        for (int s = 0; s < 8; s++) {
            float4 x = *(const float4*)&wr[s * 16 + lk * 8];
            float4 y = *(const float4*)&wr[s * 16 + lk * 8 + 4];
            bfrag[ct][s] = pack8(x, y);
        }
    }

    for (int ci = blockIdx.x; ci < 782; ci += 256) {
        const int r0 = ci * 64 + rg * 32;
        int row = r0 + lr; if (row > NA - 1) row = NA - 1;
        const float* ar = &atom[(size_t)row * FD];
        short8 afrag[8];
#pragma unroll
        for (int s = 0; s < 8; s++) {
            float4 x = *(const float4*)&ar[s * 16 + lk * 8];
            float4 y = *(const float4*)&ar[s * 16 + lk * 8 + 4];
            afrag[s] = pack8(x, y);
        }
        f32x16 acc[4];
#pragma unroll
        for (int ct = 0; ct < 4; ct++)
#pragma unroll
            for (int p = 0; p < 16; p++) acc[ct][p] = 0.f;
#pragma unroll
        for (int s = 0; s < 8; s++)
#pragma unroll
            for (int ct = 0; ct < 4; ct++)
                acc[ct] = __builtin_amdgcn_mfma_f32_32x32x16_bf16(
                              afrag[s], bfrag[ct][s], acc[ct], 0, 0, 0);
#pragma unroll
        for (int ct = 0; ct < 4; ct++) {
            const int c = cg * 128 + ct * 32 + lr;
#pragma unroll
            for (int p = 0; p < 16; p++) {
                int r = r0 + (p & 3) + 8 * (p >> 2) + 4 * lk;
                if (r < NA)
                    P12[(size_t)r * 512 + yb * 256 + c] =
                        (u16)(f2bf_bits(acc[ct][p]) >> 16);
            }
        }
    }
}

// ---------------------------------------------------------------------------
// K2 (pass A, BN1 stats): EXACT round-2 version (proven ~165 us, VGPR 124).
// 64-row tiles, stationary B, f32 LDS-transposed epilogue with coalesced
// uint2 P12 reads, A-row software prefetch. launch_bounds(256,2) only.
// ---------------------------------------------------------------------------
__global__ __launch_bounds__(256, 2) void k2_stats(const float* __restrict__ nbr,
                                                   const int* __restrict__ nidx,
                                                   const float* __restrict__ W,
                                                   const u16* __restrict__ P12,
                                                   float* __restrict__ partial1) {
    __shared__ float C_lds[64 * 256];     // 64 KB
    const int t  = threadIdx.x;
    const int w  = t >> 6;
    const int L  = t & 63;
    const int rg = w & 1;
    const int cg = w >> 1;
    const int lr = L & 31;
    const int lk = L >> 5;

    // stationary B frags: B[k][n] = W[n][256+k]
    short8 bfrag[4][4];
#pragma unroll
    for (int ct = 0; ct < 4; ct++) {
        const float* wr = &W[(size_t)(cg * 128 + ct * 32 + lr) * KIN + 256];
#pragma unroll
        for (int s = 0; s < 4; s++) {
            float4 x = *(const float4*)&wr[s * 16 + lk * 8];
            float4 y = *(const float4*)&wr[s * 16 + lk * 8 + 4];
            bfrag[ct][s] = pack8(x, y);
        }
    }

    const int c0 = (t & 63) * 4;
    float ssum[4] = {0.f, 0.f, 0.f, 0.f};
    float ssq[4]  = {0.f, 0.f, 0.f, 0.f};

    int tile = blockIdx.x;
    float4 a0[4], a1[4];
    {
        const float* ar = &nbr[(size_t)(tile * 64 + rg * 32 + lr) * KD];
#pragma unroll
        for (int s = 0; s < 4; s++) {
            a0[s] = *(const float4*)&ar[s * 16 + lk * 8];
            a1[s] = *(const float4*)&ar[s * 16 + lk * 8 + 4];
        }
    }

    for (; tile < NT2; tile += NBLK2) {
        short8 af[4];
#pragma unroll
        for (int s = 0; s < 4; s++) af[s] = pack8(a0[s], a1[s]);

        // prefetch next tile's A rows (flies over C-stage + epilogue)
        const int next = tile + NBLK2;
        if (next < NT2) {
            const float* ar = &nbr[(size_t)(next * 64 + rg * 32 + lr) * KD];
#pragma unroll
            for (int s = 0; s < 4; s++) {
                a0[s] = *(const float4*)&ar[s * 16 + lk * 8];
                a1[s] = *(const float4*)&ar[s * 16 + lk * 8 + 4];
            }
        }

        f32x16 acc[4];
#pragma unroll
        for (int ct = 0; ct < 4; ct++)
#pragma unroll
            for (int p = 0; p < 16; p++) acc[ct][p] = 0.f;
#pragma unroll
        for (int s = 0; s < 4; s++)
#pragma unroll
            for (int ct = 0; ct < 4; ct++)
                acc[ct] = __builtin_amdgcn_mfma_f32_32x32x16_bf16(
                              af[s], bfrag[ct][s], acc[ct], 0, 0, 0);

        __syncthreads();   // previous tile's epilogue reads complete
#pragma unroll
        for (int ct = 0; ct < 4; ct++) {
            const int col = cg * 128 + ct * 32 + lr;
#pragma unroll
            for (int p = 0; p < 16; p++) {
                int r = rg * 32 + (p & 3) + 8 * (p >> 2) + 4 * lk;
                C_lds[r * 256 + col] = acc[ct][p];
            }
        }
        __syncthreads();

        // linear epilogue: wave w -> rows w, w+4, ..., w+60
#pragma unroll 8
        for (int rr = 0; rr < 16; rr++) {
            const int lrow = rr * 4 + w;
            const int g    = tile * 64 + lrow;
            const u32 n    = (u32)g / 12u;
            const int iv   = nidx[g];
            const float mk = (iv != 0) ? 1.f : 0.f;
            float4 q = *(const float4*)&C_lds[lrow * 256 + c0];
            uint2 u1 = *(const uint2*)&P12[(size_t)n * 512 + c0];
            uint2 u2 = *(const uint2*)&P12[(size_t)iv * 512 + 256 + c0];
            float v0 = bflo(u1.x) + mk * (bflo(u2.x) + q.x);
            float v1 = bfhi(u1.x) + mk * (bfhi(u2.x) + q.y);
            float v2 = bflo(u1.y) + mk * (bflo(u2.y) + q.z);
            float v3 = bfhi(u1.y) + mk * (bfhi(u2.y) + q.w);
            ssum[0] += v0; ssq[0] = fmaf(v0, v0, ssq[0]);
            ssum[1] += v1; ssq[1] = fmaf(v1, v1, ssq[1]);
            ssum[2] += v2; ssq[2] = fmaf(v2, v2, ssq[2]);
            ssum[3] += v3; ssq[3] = fmaf(v3, v3, ssq[3]);
        }
    }

    // block-level column reduction -> partial1[block][512]
    __syncthreads();
#pragma unroll
    for (int qq = 0; qq < 4; qq++) C_lds[w * 256 + c0 + qq] = ssum[qq];
    __syncthreads();
    {
        float s = C_lds[t] + C_lds[256 + t] + C_lds[512 + t] + C_lds[768 + t];
        partial1[(size_t)blockIdx.x * 512 + t] = s;
    }
    __syncthreads();
#pragma unroll
    for (int qq = 0; qq < 4; qq++) C_lds[w * 256 + c0 + qq] = ssq[qq];
    __syncthreads();
    {
        float s = C_lds[t] + C_lds[256 + t] + C_lds[512 + t] + C_lds[768 + t];
        partial1[(size_t)blockIdx.x * 512 + 256 + t] = s;
    }
}

// ---------------------------------------------------------------------------
// K2b: finalize BN1 (256 threads: 2 strided iters + 2-level reduce)
// ---------------------------------------------------------------------------
__global__ __launch_bounds__(256) void k2b_bn1(const float* __restrict__ partial1,
                                               const float* __restrict__ gamma1,
                                               const float* __restrict__ beta1,
                                               float* __restrict__ bn1) {
    __shared__ double sh[8];
    const int c = blockIdx.x;
    const int t = threadIdx.x;
    double s = 0.0, q = 0.0;
    for (int b = t; b < NBLK2; b += 256) {
        s += (double)partial1[(size_t)b * 512 + c];
        q += (double)partial1[(size_t)b * 512 + 256 + c];
    }
#pragma unroll
    for (int off = 32; off > 0; off >>= 1) {
        s += __shfl_down(s, off);
        q += __shfl_down(q, off);
    }
    if ((t & 63) == 0) { sh[(t >> 6) * 2] = s; sh[(t >> 6) * 2 + 1] = q; }
    __syncthreads();
    if (t == 0) {
        s = sh[0] + sh[2] + sh[4] + sh[6];
        q = sh[1] + sh[3] + sh[5] + sh[7];
        double mean = s / (double)NMR;
        double var  = q / (double)NMR - mean * mean;
        float scale = gamma1[c] * rsqrtf((float)var + BN_EPS);
        bn1[c]       = scale;
        bn1[256 + c] = fmaf(-(float)mean, scale, beta1[c]);
    }
}

// ---------------------------------------------------------------------------
// K3 (pass B): UNCHANGED (172 us). Block = 96 edge rows = 8 atoms; MFMA Q ->
// bf16 LDS; column-parallel epilogue, coalesced 256B P12 bursts.
// ---------------------------------------------------------------------------
__global__ __launch_bounds__(256, 3) void k3_fused(const float* __restrict__ nbr,
                                                   const int* __restrict__ nidx,
                                                   const float* __restrict__ W,
                                                   const u16* __restrict__ P12,
                                                   const float* __restrict__ bn1,
                                                   float* __restrict__ nsum,
                                                   float* __restrict__ partial2) {
    __shared__ u16 Q[96 * 256];   // 48 KB bf16 Q-tile
    const int t  = threadIdx.x;
    const int w  = t >> 6;
    const int L  = t & 63;
    const int lr = L & 31, lk = L >> 5;

    // stationary B frags: cols w*64 + ct*32 + lr, k in [256,320)
    short8 bfrag[2][4];
#pragma unroll
    for (int ct = 0; ct < 2; ct++) {
        const float* wr = &W[(size_t)(w * 64 + ct * 32 + lr) * KIN + 256];
#pragma unroll
        for (int s = 0; s < 4; s++) {
            float4 x = *(const float4*)&wr[s * 16 + lk * 8];
            float4 y = *(const float4*)&wr[s * 16 + lk * 8 + 4];
            bfrag[ct][s] = pack8(x, y);
        }
    }

    const int rbase = blockIdx.x * 96;
#pragma unroll 1
    for (int st = 0; st < 3; st++) {
        const float* ar = &nbr[(size_t)(rbase + st * 32 + lr) * KD + lk * 8];
        f32x16 acc[2];
#pragma unroll
        for (int p = 0; p < 16; p++) { acc[0][p] = 0.f; acc[1][p] = 0.f; }
#pragma unroll
        for (int s = 0; s < 4; s++) {
            float4 x = *(const float4*)&ar[s * 16];
            float4 y = *(const float4*)&ar[s * 16 + 4];
            short8 af = pack8(x, y);
            acc[0] = __builtin_amdgcn_mfma_f32_32x32x16_bf16(af, bfrag[0][s], acc[0], 0, 0, 0);
            acc[1] = __builtin_amdgcn_mfma_f32_32x32x16_bf16(af, bfrag[1][s], acc[1], 0, 0, 0);
        }
#pragma unroll
        for (int ct = 0; ct < 2; ct++) {
            const int col = w * 64 + ct * 32 + lr;
#pragma unroll
            for (int p = 0; p < 16; p++) {
                const int row = st * 32 + (p & 3) + 8 * (p >> 2) + 4 * lk;
                Q[row * 256 + col] = (u16)(f2bf_bits(acc[ct][p]) >> 16);
            }
        }
    }
    __syncthreads();

    // epilogue: thread -> (atom a, filter cols c0..c0+3; core cols +128)
    const int a  = t >> 5;            // 0..7
    const int c0 = (t & 31) * 4;      // filter col base
    const int n  = blockIdx.x * 8 + a;

    float4 scf = *(const float4*)&bn1[c0];
    float4 shf = *(const float4*)&bn1[256 + c0];
    float4 scc = *(const float4*)&bn1[128 + c0];
    float4 shc = *(const float4*)&bn1[384 + c0];

    uint2 u1f = *(const uint2*)&P12[(size_t)n * 512 + c0];
    uint2 u1c = *(const uint2*)&P12[(size_t)n * 512 + 128 + c0];
    const float p1f0 = bflo(u1f.x), p1f1 = bfhi(u1f.x), p1f2 = bflo(u1f.y), p1f3 = bfhi(u1f.y);
    const float p1c0 = bflo(u1c.x), p1c1 = bfhi(u1c.x), p1c2 = bflo(u1c.y), p1c3 = bfhi(u1c.y);

    float s4[4] = {0.f, 0.f, 0.f, 0.f};
#pragma unroll
    for (int m = 0; m < 12; m++) {
        const int g  = n * 12 + m;
        const int iv = nidx[g];
        const float mk = (iv != 0) ? 1.f : 0.f;
        const int row = a * 12 + m;
        uint2 qf  = *(const uint2*)&Q[row * 256 + c0];
        uint2 qc  = *(const uint2*)&Q[row * 256 + 128 + c0];
        uint2 u2f = *(const uint2*)&P12[(size_t)iv * 512 + 256 + c0];
        uint2 u2c = *(const uint2*)&P12[(size_t)iv * 512 + 384 + c0];

        float vf0 = p1f0 + mk * (bflo(u2f.x) + bflo(qf.x));
        float vf1 = p1f1 + mk * (bfhi(u2f.x) + bfhi(qf.x));
        float vf2 = p1f2 + mk * (bflo(u2f.y) + bflo(qf.y));
        float vf3 = p1f3 + mk * (bfhi(u2f.y) + bfhi(qf.y));
        float vc0 = p1c0 + mk * (bflo(u2c.x) + bflo(qc.x));
        float vc1 = p1c1 + mk * (bfhi(u2c.x) + bfhi(qc.x));
        float vc2 = p1c2 + mk * (bflo(u2c.y) + bflo(qc.y));
        float vc3 = p1c3 + mk * (bfhi(u2c.y) + bfhi(qc.y));

        float xf0 = fmaf(vf0, scf.x, shf.x), xc0 = fmaf(vc0, scc.x, shc.x);
        float xf1 = fmaf(vf1, scf.y, shf.y), xc1 = fmaf(vc1, scc.y, shc.y);
        float xf2 = fmaf(vf2, scf.z, shf.z), xc2 = fmaf(vc2, scc.z, shc.z);
        float xf3 = fmaf(vf3, scf.w, shf.w), xc3 = fmaf(vc3, scc.w, shc.w);

        s4[0] += fast_sigmoid(xf0) * fast_softplus(xc0) * mk;
        s4[1] += fast_sigmoid(xf1) * fast_softplus(xc1) * mk;
        s4[2] += fast_sigmoid(xf2) * fast_softplus(xc2) * mk;
        s4[3] += fast_sigmoid(xf3) * fast_softplus(xc3) * mk;
    }

    *(float4*)&nsum[(size_t)n * 128 + c0] = make_float4(s4[0], s4[1], s4[2], s4[3]);

    // BN2 partials: reuse Q LDS as float scratch (8 KB needed)
    __syncthreads();
    float* red = (float*)Q;
#pragma unroll
    for (int j = 0; j < 4; j++) {
        red[a * 128 + c0 + j]        = s4[j];
        red[1024 + a * 128 + c0 + j] = s4[j] * s4[j];
    }
    __syncthreads();
    if (t < 128) {
        float s = 0.f, q = 0.f;
#pragma unroll
        for (int a2 = 0; a2 < 8; a2++) {
            s += red[a2 * 128 + t];
            q += red[1024 + a2 * 128 + t];
        }
        partial2[(size_t)blockIdx.x * 256 + t]       = s;
        partial2[(size_t)blockIdx.x * 256 + 128 + t] = q;
    }
}

// ---------------------------------------------------------------------------
// K3b: finalize BN2 (256 threads: ~25 strided iters + 2-level reduce;
// old 64-thread version had a 98-iteration latency chain)
// ---------------------------------------------------------------------------
__global__ __launch_bounds__(256) void k3b_bn2(const float* __restrict__ partial2,
                                               const float* __restrict__ gamma2,
                                               const float* __restrict__ beta2,
                                               float* __restrict__ bn2) {
    __shared__ double sh[8];
    const int c = blockIdx.x;
    const int t = threadIdx.x;
    double s = 0.0, q = 0.0;
    for (int b = t; b < NBLKB; b += 256) {
        s += (double)partial2[(size_t)b * 256 + c];
        q += (double)partial2[(size_t)b * 256 + 128 + c];
    }
#pragma unroll
    for (int off = 32; off > 0; off >>= 1) {
        s += __shfl_down(s, off);
        q += __shfl_down(q, off);
    }
    if ((t & 63) == 0) { sh[(t >> 6) * 2] = s; sh[(t >> 6) * 2 + 1] = q; }
    __syncthreads();
    if (t == 0) {
        s = sh[0] + sh[2] + sh[4] + sh[6];
        q = sh[1] + sh[3] + sh[5] + sh[7];
        double mean = s / (double)NA;
        double var  = q / (double)NA - mean * mean;
        float scale = gamma2[c] * rsqrtf((float)var + BN_EPS);
        bn2[c]       = scale;
        bn2[128 + c] = fmaf(-(float)mean, scale, beta2[c]);
    }
}

// ---------------------------------------------------------------------------
// K4: out = softplus(atom_in + nbr_sumed*scale2 + shift2)
// ---------------------------------------------------------------------------
__global__ __launch_bounds__(256) void k4_out(const float* __restrict__ atom,
                                              const float* __restrict__ nsum,
                                              const float* __restrict__ bn2,
                                              float* __restrict__ out) {
    const int i  = blockIdx.x * 256 + threadIdx.x;   // float4 index, 1.6M exact
    const int c0 = (i & 31) * 4;
    float4 a = ((const float4*)atom)[i];
    float4 s = ((const float4*)nsum)[i];
    float4 r;
    r.x = fast_softplus(a.x + fmaf(s.x, bn2[c0 + 0], bn2[128 + c0 + 0]));
    r.y = fast_softplus(a.y + fmaf(s.y, bn2[c0 + 1], bn2[128 + c0 + 1]));
    r.z = fast_softplus(a.z + fmaf(s.z, bn2[c0 + 2], bn2[128 + c0 + 2]));
    r.w = fast_softplus(a.w + fmaf(s.w, bn2[c0 + 3], bn2[128 + c0 + 3]));
    ((float4*)out)[i] = r;
}

// ---------------------------------------------------------------------------
extern "C" void kernel_launch(void* const* d_in, const int* in_sizes, int n_in,
                              void* d_out, int out_size, void* d_ws, size_t ws_size,
                              hipStream_t stream) {
    const float* atom   = (const float*)d_in[0];
    const float* nbr    = (const float*)d_in[1];
    const int*   nidx   = (const int*)d_in[2];
    const float* W      = (const float*)d_in[3];
    // d_in[4] = b : unused — cancels exactly through BN1 mean subtraction
    const float* gamma1 = (const float*)d_in[5];
    const float* beta1  = (const float*)d_in[6];
    const float* gamma2 = (const float*)d_in[7];
    const float* beta2  = (const float*)d_in[8];
    float* out = (float*)d_out;

    // ws layout: P12 bf16 (51.2MB) | nsum (25.6MB) | partial1 | partial2 | bn
    u16* P12        = (u16*)d_ws;
    float* nsum     = (float*)(P12 + (size_t)NA * 512);
    float* partial1 = nsum + (size_t)NA * 128;
    float* partial2 = partial1 + (size_t)NBLK2 * 512;
    float* bn1      = partial2 + (size_t)NBLKB * 256;
    float* bn2      = bn1 + 512;

    k1_p12  <<<dim3(256, 2), 256, 0, stream>>>(atom, W, P12);
    k2_stats<<<NBLK2,        256, 0, stream>>>(nbr, nidx, W, P12, partial1);
    k2b_bn1 <<<256,          256, 0, stream>>>(partial1, gamma1, beta1, bn1);
    k3_fused<<<NBLKB,        256, 0, stream>>>(nbr, nidx, W, P12, bn1, nsum, partial2);
    k3b_bn2 <<<128,          256, 0, stream>>>(partial2, gamma2, beta2, bn2);
    k4_out  <<<6250,         256, 0, stream>>>(atom, nsum, bn2, out);
}